// Round 1
// baseline (1076.053 us; speedup 1.0000x reference)
//
#include <hip/hip_runtime.h>

typedef _Float16 half_t;
typedef _Float16 half2v __attribute__((ext_vector_type(2)));
typedef _Float16 half4v __attribute__((ext_vector_type(4)));
typedef _Float16 half8v __attribute__((ext_vector_type(8)));
typedef float    float4v __attribute__((ext_vector_type(4)));
typedef short    short8v __attribute__((ext_vector_type(8)));

#define S_IMG 2048
#define S_TXT 512
#define S_TOT 2560
#define NH    24
#define HD    128
#define DM    3072

// async global->LDS, 16B per lane, wave-uniform LDS base
__device__ __forceinline__ void gload16(const void* g, void* l) {
  __builtin_amdgcn_global_load_lds(
      (const __attribute__((address_space(1))) unsigned int*)g,
      (__attribute__((address_space(3))) unsigned int*)l, 16, 0, 0);
}

// ---------------------------------------------------------------- f32 -> f16
__global__ void cvt_kernel(const float* __restrict__ s, half_t* __restrict__ d, int n) {
  int i = (blockIdx.x * 256 + threadIdx.x) * 4;
  int stride = gridDim.x * 256 * 4;
  for (; i < n; i += stride) {
    float4v v = *(const float4v*)(s + i);
    half4v h;
    h[0] = (half_t)v[0]; h[1] = (half_t)v[1]; h[2] = (half_t)v[2]; h[3] = (half_t)v[3];
    *(half4v*)(d + i) = h;
  }
}

// ------------------------------------------------ GEMM  C[m,n] = A[m,:]·Bt[n,:] + bias[n]
// A: [M,K] f16 row-major, Bt: [N,K] f16 row-major (i.e. W as given), 128x128 tile, BK=32
template <typename OUT>
__global__ __launch_bounds__(256) void gemm_bt(const half_t* __restrict__ A,
                                               const half_t* __restrict__ Bt,
                                               const float* __restrict__ bias,
                                               OUT* __restrict__ C, int M, int N, int K) {
  __shared__ half_t As[128 * 32];
  __shared__ half_t Bs[128 * 32];
  const int bm = blockIdx.y * 128, bn = blockIdx.x * 128;
  const int tid = threadIdx.x, wid = tid >> 6, l = tid & 63;
  const int wm = (wid >> 1) * 64, wn = (wid & 1) * 64;
  const int l15 = l & 15, l4 = l >> 4;
  float4v acc[4][4] = {};

  const half_t* ga = A + (long)(bm + wid * 32 + (l >> 2)) * K + (l & 3) * 8;
  const half_t* gb = Bt + (long)(bn + wid * 32 + (l >> 2)) * K + (l & 3) * 8;
  char* lAs = (char*)As + wid * 2048;
  char* lBs = (char*)Bs + wid * 2048;
  const long rowstep = 16l * K;

  for (int k0 = 0; k0 < K; k0 += 32) {
    gload16(ga + k0, lAs);
    gload16(ga + rowstep + k0, lAs + 1024);
    gload16(gb + k0, lBs);
    gload16(gb + rowstep + k0, lBs + 1024);
    __syncthreads();
    half8v af[4], bf[4];
#pragma unroll
    for (int i = 0; i < 4; i++) af[i] = *(const half8v*)&As[(wm + i * 16 + l15) * 32 + l4 * 8];
#pragma unroll
    for (int j = 0; j < 4; j++) bf[j] = *(const half8v*)&Bs[(wn + j * 16 + l15) * 32 + l4 * 8];
#pragma unroll
    for (int i = 0; i < 4; i++)
#pragma unroll
      for (int j = 0; j < 4; j++)
        acc[i][j] = __builtin_amdgcn_mfma_f32_16x16x32_f16(af[i], bf[j], acc[i][j], 0, 0, 0);
    __syncthreads();
  }
#pragma unroll
  for (int i = 0; i < 4; i++)
#pragma unroll
    for (int j = 0; j < 4; j++) {
      int row = bm + wm + i * 16 + l4 * 4;
      int col = bn + wn + j * 16 + l15;
      float bv = bias ? bias[col] : 0.0f;
#pragma unroll
      for (int r = 0; r < 4; r++) {
        float v = acc[i][j][r] + bv;
        C[(long)(row + r) * N + col] = (OUT)v;
      }
    }
}

// ------------------------------------------------ ip projections (M=4, f32 direct)
// out[p][n] = sum_k x[p][k] * W[n][k]
__global__ __launch_bounds__(256) void ip_proj_kernel(const float* __restrict__ x,
                                                      const float* __restrict__ W,
                                                      float* __restrict__ out) {
  int n = blockIdx.x * 4 + (threadIdx.x >> 6);
  int l = threadIdx.x & 63;
  const float* wr = W + (long)n * DM;
  float acc[4] = {0.f, 0.f, 0.f, 0.f};
  for (int k = l * 4; k < DM; k += 256) {
    float4v wv = *(const float4v*)(wr + k);
#pragma unroll
    for (int p = 0; p < 4; p++) {
      float4v xv = *(const float4v*)(x + p * DM + k);
      acc[p] += wv[0] * xv[0] + wv[1] * xv[1] + wv[2] * xv[2] + wv[3] * xv[3];
    }
  }
#pragma unroll
  for (int off = 32; off; off >>= 1)
#pragma unroll
    for (int p = 0; p < 4; p++) acc[p] += __shfl_xor(acc[p], off, 64);
  if (l == 0)
#pragma unroll
    for (int p = 0; p < 4; p++) out[p * DM + n] = acc[p];
}

// ------------------------------------------------ ip k-norm (eps 1e-5, no weight) + v convert
__global__ void ip_norm_kernel(const float* __restrict__ kr, const float* __restrict__ vr,
                               half_t* __restrict__ kh, half_t* __restrict__ vh) {
  int t = blockIdx.x;
  int l = threadIdx.x;
  int d = l * 2;
  if (t < 96) {
    int base = (t / 24) * DM + (t % 24) * HD;
    float x0 = kr[base + d], x1 = kr[base + d + 1];
    float ss = x0 * x0 + x1 * x1;
#pragma unroll
    for (int off = 32; off; off >>= 1) ss += __shfl_xor(ss, off, 64);
    float r = rsqrtf(ss * (1.0f / HD) + 1e-5f);
    kh[base + d] = (half_t)(x0 * r);
    kh[base + d + 1] = (half_t)(x1 * r);
  } else {
    int t2 = t - 96;
    int base = (t2 / 24) * DM + (t2 % 24) * HD;
    vh[base + d] = (half_t)vr[base + d];
    vh[base + d + 1] = (half_t)vr[base + d + 1];
  }
}

// ------------------------------------------------ prep: rmsnorm + rope + concat -> [NH][S_TOT][HD]
__global__ __launch_bounds__(256) void prep_kernel(
    const half_t* __restrict__ qraw, const half_t* __restrict__ kraw, const half_t* __restrict__ vraw,
    const half_t* __restrict__ eq, const half_t* __restrict__ ek, const half_t* __restrict__ ev,
    const float* __restrict__ nqw, const float* __restrict__ nkw,
    const float* __restrict__ naqw, const float* __restrict__ nakw,
    const float* __restrict__ cosb, const float* __restrict__ sinb,
    half_t* __restrict__ qcat, half_t* __restrict__ kcat, half_t* __restrict__ vcat,
    half_t* __restrict__ qnr) {
  int task = blockIdx.x * 4 + (threadIdx.x >> 6);  // 2560*24 tasks
  int l = threadIdx.x & 63;
  int s = task / NH, h = task - (task / NH) * NH;
  int d = l * 2;
  const half_t *qs, *ks, *vs;
  const float *wq, *wk;
  if (s < S_TXT) {
    long base = (long)s * DM + h * HD;
    qs = eq + base; ks = ek + base; vs = ev + base;
    wq = naqw; wk = nakw;
  } else {
    long base = (long)(s - S_TXT) * DM + h * HD;
    qs = qraw + base; ks = kraw + base; vs = vraw + base;
    wq = nqw; wk = nkw;
  }
  half2v qv = *(const half2v*)(qs + d);
  half2v kv = *(const half2v*)(ks + d);
  half2v vv = *(const half2v*)(vs + d);
  float q0 = (float)qv[0], q1 = (float)qv[1];
  float k0 = (float)kv[0], k1 = (float)kv[1];
  float ssq = q0 * q0 + q1 * q1;
  float ssk = k0 * k0 + k1 * k1;
#pragma unroll
  for (int off = 32; off; off >>= 1) {
    ssq += __shfl_xor(ssq, off, 64);
    ssk += __shfl_xor(ssk, off, 64);
  }
  float rq = rsqrtf(ssq * (1.0f / HD) + 1e-6f);
  float rk = rsqrtf(ssk * (1.0f / HD) + 1e-6f);
  float qn0 = q0 * rq * wq[d], qn1 = q1 * rq * wq[d + 1];
  float kn0 = k0 * rk * wk[d], kn1 = k1 * rk * wk[d + 1];
  if (s >= S_TXT) {
    half2v o; o[0] = (half_t)qn0; o[1] = (half_t)qn1;
    *(half2v*)(qnr + ((long)h * S_IMG + (s - S_TXT)) * HD + d) = o;
  }
  float c0 = cosb[s * HD + d], c1 = cosb[s * HD + d + 1];
  float s0 = sinb[s * HD + d], s1 = sinb[s * HD + d + 1];
  float qo0 = qn0 * c0 - qn1 * s0, qo1 = qn1 * c1 + qn0 * s1;
  float ko0 = kn0 * c0 - kn1 * s0, ko1 = kn1 * c1 + kn0 * s1;
  long ci = ((long)h * S_TOT + s) * HD + d;
  half2v oq; oq[0] = (half_t)qo0; oq[1] = (half_t)qo1;
  half2v ok; ok[0] = (half_t)ko0; ok[1] = (half_t)ko1;
  *(half2v*)(qcat + ci) = oq;
  *(half2v*)(kcat + ci) = ok;
  *(half2v*)(vcat + ci) = vv;
}

// ------------------------------------------------ ip attention (4 keys) -> ip_out [S_IMG][DM]
__global__ __launch_bounds__(256) void ip_attn_kernel(const half_t* __restrict__ qnr,
                                                      const half_t* __restrict__ kh,
                                                      const half_t* __restrict__ vh,
                                                      half_t* __restrict__ ipout) {
  int task = blockIdx.x * 4 + (threadIdx.x >> 6);  // NH * S_IMG
  int l = threadIdx.x & 63;
  int h = task >> 11;
  int s = task & 2047;
  int d = l * 2;
  half2v qv = *(const half2v*)(qnr + ((long)h * S_IMG + s) * HD + d);
  float q0 = (float)qv[0], q1 = (float)qv[1];
  float sc[4];
#pragma unroll
  for (int p = 0; p < 4; p++) {
    half2v kv = *(const half2v*)(kh + p * DM + h * HD + d);
    sc[p] = q0 * (float)kv[0] + q1 * (float)kv[1];
  }
#pragma unroll
  for (int off = 32; off; off >>= 1)
#pragma unroll
    for (int p = 0; p < 4; p++) sc[p] += __shfl_xor(sc[p], off, 64);
  float m = fmaxf(fmaxf(sc[0], sc[1]), fmaxf(sc[2], sc[3]));
  float e[4], sum = 0.f;
#pragma unroll
  for (int p = 0; p < 4; p++) { e[p] = __expf((sc[p] - m) * 0.088388347648318447f); sum += e[p]; }
  float inv = 1.0f / sum;
  float o0 = 0.f, o1 = 0.f;
#pragma unroll
  for (int p = 0; p < 4; p++) {
    half2v vv = *(const half2v*)(vh + p * DM + h * HD + d);
    o0 += e[p] * (float)vv[0];
    o1 += e[p] * (float)vv[1];
  }
  o0 *= inv; o1 *= inv;
  half2v ov; ov[0] = (half_t)o0; ov[1] = (half_t)o1;
  *(half2v*)(ipout + (long)s * DM + h * HD + d) = ov;
}

// ------------------------------------------------ flash attention over concat seq
// grid (S_TOT/64, NH); 4 waves x 16 q-rows; KV tile 32
__global__ __launch_bounds__(256) void flash_kernel(const half_t* __restrict__ qcat,
                                                    const half_t* __restrict__ kcat,
                                                    const half_t* __restrict__ vcat,
                                                    const half_t* __restrict__ ipout,
                                                    const float* __restrict__ lsp,
                                                    half_t* __restrict__ ocomb) {
  __shared__ half_t Ks[32 * 128];     // XOR-swizzled
  __shared__ short  Vt[128 * 40];     // transposed, padded rows (80B, 16B-aligned)
  __shared__ half_t Pl[4][16 * 40];   // per-wave P tile, padded
  const int h = blockIdx.y, qb = blockIdx.x;
  const int tid = threadIdx.x, wid = tid >> 6, l = tid & 63;
  const int l15 = l & 15, l4 = l >> 4;
  const float CEXP = (float)(0.088388347648318447 * 1.4426950408889634);

  half8v qf[4];
  {
    int qrow = qb * 64 + wid * 16 + l15;
    const half_t* qp = qcat + ((long)h * S_TOT + qrow) * HD;
#pragma unroll
    for (int ks = 0; ks < 4; ks++) qf[ks] = *(const half8v*)(qp + ks * 32 + l4 * 8);
  }
  float4v o[8] = {};
  float mreg[4] = {-3.0e38f, -3.0e38f, -3.0e38f, -3.0e38f};
  float lreg[4] = {0.f, 0.f, 0.f, 0.f};
  const float ls = lsp[0];
  const int vk = tid & 31, vd0 = (tid >> 5) * 8;

  for (int kt = 0; kt < S_TOT; kt += 32) {
    // stage K (swizzled)
#pragma unroll
    for (int i = 0; i < 2; i++) {
      int b = tid * 32 + i * 16;
      int row = b >> 8, c = b & 255;
      short8v kv = *(const short8v*)(kcat + ((long)h * S_TOT + kt + row) * HD + (c >> 1));
      int sb = (row << 8) | (c ^ ((row & 7) << 4));
      *(short8v*)((char*)Ks + sb) = kv;
    }
    // stage V transposed
#pragma unroll
    for (int i = 0; i < 2; i++) {
      int dd = vd0 + i * 64;
      short8v vv = *(const short8v*)(vcat + ((long)h * S_TOT + kt + vk) * HD + dd);
#pragma unroll
      for (int j = 0; j < 8; j++) Vt[(dd + j) * 40 + vk] = vv[j];
    }
    __syncthreads();

    // QK^T : S tile 16(q) x 32(k')
    float4v s0 = {}, s1 = {};
#pragma unroll
    for (int ks = 0; ks < 4; ks++) {
      int r0 = l15, r1 = 16 + l15;
      int b0 = ((r0 << 8) + ks * 64 + l4 * 16) ^ ((r0 & 7) << 4);
      int b1 = ((r1 << 8) + ks * 64 + l4 * 16) ^ ((r1 & 7) << 4);
      half8v kf0 = *(const half8v*)((char*)Ks + b0);
      half8v kf1 = *(const half8v*)((char*)Ks + b1);
      s0 = __builtin_amdgcn_mfma_f32_16x16x32_f16(qf[ks], kf0, s0, 0, 0, 0);
      s1 = __builtin_amdgcn_mfma_f32_16x16x32_f16(qf[ks], kf1, s1, 0, 0, 0);
    }
    // online softmax (rows: q = l4*4 + r, cols: k' = nb*16 + l15)
    float mt[4], p0[4], p1[4], al[4];
#pragma unroll
    for (int r = 0; r < 4; r++) mt[r] = fmaxf(s0[r], s1[r]);
#pragma unroll
    for (int off = 8; off; off >>= 1)
#pragma unroll
      for (int r = 0; r < 4; r++) mt[r] = fmaxf(mt[r], __shfl_xor(mt[r], off, 16));
#pragma unroll
    for (int r = 0; r < 4; r++) {
      float mn = fmaxf(mreg[r], mt[r]);
      al[r] = exp2f((mreg[r] - mn) * CEXP);
      mreg[r] = mn;
      p0[r] = exp2f((s0[r] - mn) * CEXP);
      p1[r] = exp2f((s1[r] - mn) * CEXP);
    }
    float rs[4];
#pragma unroll
    for (int r = 0; r < 4; r++) rs[r] = p0[r] + p1[r];
#pragma unroll
    for (int off = 8; off; off >>= 1)
#pragma unroll
      for (int r = 0; r < 4; r++) rs[r] += __shfl_xor(rs[r], off, 16);
#pragma unroll
    for (int r = 0; r < 4; r++) lreg[r] = lreg[r] * al[r] + rs[r];
#pragma unroll
    for (int cb = 0; cb < 8; cb++)
#pragma unroll
      for (int r = 0; r < 4; r++) o[cb][r] *= al[r];
    // P -> LDS (transpose to A-operand layout)
#pragma unroll
    for (int r = 0; r < 4; r++) {
      int qr = l4 * 4 + r;
      Pl[wid][qr * 40 + l15] = (half_t)p0[r];
      Pl[wid][qr * 40 + 16 + l15] = (half_t)p1[r];
    }
    half8v pa = *(const half8v*)&Pl[wid][l15 * 40 + l4 * 8];
    // PV
#pragma unroll
    for (int cb = 0; cb < 8; cb++) {
      half8v vf = *(const half8v*)&Vt[(cb * 16 + l15) * 40 + l4 * 8];
      o[cb] = __builtin_amdgcn_mfma_f32_16x16x32_f16(pa, vf, o[cb], 0, 0, 0);
    }
    __syncthreads();
  }
  // epilogue: normalize, add ls*ip_out for img rows, write f16
#pragma unroll
  for (int r = 0; r < 4; r++) {
    float inv = 1.0f / lreg[r];
    int s = qb * 64 + wid * 16 + l4 * 4 + r;
#pragma unroll
    for (int cb = 0; cb < 8; cb++) {
      int col = h * HD + cb * 16 + l15;
      float val = o[cb][r] * inv;
      if (s >= S_TXT) val += ls * (float)ipout[(long)(s - S_TXT) * DM + col];
      ocomb[(long)s * DM + col] = (half_t)val;
    }
  }
}

// ================================================================ host
extern "C" void kernel_launch(void* const* d_in, const int* in_sizes, int n_in,
                              void* d_out, int out_size, void* d_ws, size_t ws_size,
                              hipStream_t stream) {
  (void)in_sizes; (void)n_in; (void)out_size; (void)ws_size;
  const float* hs    = (const float*)d_in[0];
  const float* enc   = (const float*)d_in[1];
  const float* ipenc = (const float*)d_in[2];
  const float* lsc   = (const float*)d_in[3];
  const float* Wq  = (const float*)d_in[4];  const float* bq  = (const float*)d_in[5];
  const float* Wk  = (const float*)d_in[6];  const float* bk  = (const float*)d_in[7];
  const float* Wv  = (const float*)d_in[8];  const float* bv  = (const float*)d_in[9];
  const float* nqw = (const float*)d_in[10]; const float* nkw = (const float*)d_in[11];
  const float* Waq = (const float*)d_in[12]; const float* baq = (const float*)d_in[13];
  const float* Wak = (const float*)d_in[14]; const float* bak = (const float*)d_in[15];
  const float* Wav = (const float*)d_in[16]; const float* bav = (const float*)d_in[17];
  const float* naqw= (const float*)d_in[18]; const float* nakw= (const float*)d_in[19];
  const float* Wkip= (const float*)d_in[20]; const float* Wvip= (const float*)d_in[21];
  const float* Wo  = (const float*)d_in[22]; const float* bo  = (const float*)d_in[23];
  const float* Wao = (const float*)d_in[24]; const float* bao = (const float*)d_in[25];
  const float* cosb= (const float*)d_in[26]; const float* sinb= (const float*)d_in[27];

  half_t* base = (half_t*)d_ws;
  size_t off = 0;
  auto alloc = [&](size_t n) { half_t* p = base + off; off += (n + 127) & ~(size_t)127; return p; };
  const size_t WSZ = (size_t)DM * DM;          // 9437184
  const size_t HSZ = (size_t)S_IMG * DM;       // 6291456
  const size_t ESZ = (size_t)S_TXT * DM;       // 1572864
  const size_t CSZ = (size_t)NH * S_TOT * HD;  // 7864320

  half_t* wbuf  = alloc(WSZ);
  half_t* hs_h  = alloc(HSZ);
  half_t* enc_h = alloc(ESZ);
  half_t* q_raw = alloc(HSZ);
  half_t* k_raw = alloc(HSZ);
  half_t* v_raw = alloc(HSZ);
  half_t* eq_r  = alloc(ESZ);
  half_t* ek_r  = alloc(ESZ);
  half_t* ev_r  = alloc(ESZ);
  half_t* qcat  = alloc(CSZ);
  half_t* kcat  = alloc(CSZ);
  half_t* vcat  = alloc(CSZ);
  half_t* qnr   = alloc(HSZ);
  half_t* ipout = alloc(HSZ);
  half_t* ocomb = alloc((size_t)S_TOT * DM);
  half_t* ipk_h = alloc(4 * DM);
  half_t* ipv_h = alloc(4 * DM);
  float* ipk_raw = (float*)alloc(2 * 4 * DM);
  float* ipv_raw = (float*)alloc(2 * 4 * DM);

  // activations -> f16
  cvt_kernel<<<1024, 256, 0, stream>>>(hs, hs_h, (int)HSZ);
  cvt_kernel<<<512, 256, 0, stream>>>(enc, enc_h, (int)ESZ);

  // img qkv projections (weight buffer reused; stream order serializes)
  cvt_kernel<<<2048, 256, 0, stream>>>(Wq, wbuf, (int)WSZ);
  gemm_bt<half_t><<<dim3(24, 16), 256, 0, stream>>>(hs_h, wbuf, bq, q_raw, S_IMG, DM, DM);
  cvt_kernel<<<2048, 256, 0, stream>>>(Wk, wbuf, (int)WSZ);
  gemm_bt<half_t><<<dim3(24, 16), 256, 0, stream>>>(hs_h, wbuf, bk, k_raw, S_IMG, DM, DM);
  cvt_kernel<<<2048, 256, 0, stream>>>(Wv, wbuf, (int)WSZ);
  gemm_bt<half_t><<<dim3(24, 16), 256, 0, stream>>>(hs_h, wbuf, bv, v_raw, S_IMG, DM, DM);

  // encoder projections
  cvt_kernel<<<2048, 256, 0, stream>>>(Waq, wbuf, (int)WSZ);
  gemm_bt<half_t><<<dim3(24, 4), 256, 0, stream>>>(enc_h, wbuf, baq, eq_r, S_TXT, DM, DM);
  cvt_kernel<<<2048, 256, 0, stream>>>(Wak, wbuf, (int)WSZ);
  gemm_bt<half_t><<<dim3(24, 4), 256, 0, stream>>>(enc_h, wbuf, bak, ek_r, S_TXT, DM, DM);
  cvt_kernel<<<2048, 256, 0, stream>>>(Wav, wbuf, (int)WSZ);
  gemm_bt<half_t><<<dim3(24, 4), 256, 0, stream>>>(enc_h, wbuf, bav, ev_r, S_TXT, DM, DM);

  // ip path
  ip_proj_kernel<<<768, 256, 0, stream>>>(ipenc, Wkip, ipk_raw);
  ip_proj_kernel<<<768, 256, 0, stream>>>(ipenc, Wvip, ipv_raw);
  ip_norm_kernel<<<192, 64, 0, stream>>>(ipk_raw, ipv_raw, ipk_h, ipv_h);

  // rmsnorm + rope + concat
  prep_kernel<<<(S_TOT * NH) / 4, 256, 0, stream>>>(q_raw, k_raw, v_raw, eq_r, ek_r, ev_r,
                                                    nqw, nkw, naqw, nakw, cosb, sinb,
                                                    qcat, kcat, vcat, qnr);

  // ip attention
  ip_attn_kernel<<<(NH * S_IMG) / 4, 256, 0, stream>>>(qnr, ipk_h, ipv_h, ipout);

  // main flash attention (+ fold ls*ip_out into img rows)
  flash_kernel<<<dim3(S_TOT / 64, NH), 256, 0, stream>>>(qcat, kcat, vcat, ipout, lsc, ocomb);

  // output projections -> d_out (f32)
  float* out_img = (float*)d_out;
  float* out_enc = (float*)d_out + (size_t)S_IMG * DM;
  cvt_kernel<<<2048, 256, 0, stream>>>(Wo, wbuf, (int)WSZ);
  gemm_bt<float><<<dim3(24, 16), 256, 0, stream>>>(ocomb + (size_t)S_TXT * DM, wbuf, bo, out_img, S_IMG, DM, DM);
  cvt_kernel<<<2048, 256, 0, stream>>>(Wao, wbuf, (int)WSZ);
  gemm_bt<float><<<dim3(24, 4), 256, 0, stream>>>(ocomb, wbuf, bao, out_enc, S_TXT, DM, DM);
}

// Round 3
// 721.225 us; speedup vs baseline: 1.4920x; 1.4920x over previous
//
#include <hip/hip_runtime.h>

typedef _Float16 half_t;
typedef _Float16 half2v __attribute__((ext_vector_type(2)));
typedef _Float16 half4v __attribute__((ext_vector_type(4)));
typedef _Float16 half8v __attribute__((ext_vector_type(8)));
typedef float    float4v __attribute__((ext_vector_type(4)));
typedef short    short8v __attribute__((ext_vector_type(8)));

#define S_IMG 2048
#define S_TXT 512
#define S_TOT 2560
#define NH    24
#define HD    128
#define DM    3072

// async global->LDS, 16B per lane, wave-uniform LDS base (+ lane*16 by HW)
__device__ __forceinline__ void gload16(const void* g, void* l) {
  __builtin_amdgcn_global_load_lds(
      (const __attribute__((address_space(1))) unsigned int*)g,
      (__attribute__((address_space(3))) unsigned int*)l, 16, 0, 0);
}

// ---------------------------------------------------------------- f32 -> f16
__global__ void cvt_kernel(const float* __restrict__ s, half_t* __restrict__ d, int n) {
  int i = (blockIdx.x * 256 + threadIdx.x) * 4;
  int stride = gridDim.x * 256 * 4;
  for (; i < n; i += stride) {
    float4v v = *(const float4v*)(s + i);
    half4v h;
    h[0] = (half_t)v[0]; h[1] = (half_t)v[1]; h[2] = (half_t)v[2]; h[3] = (half_t)v[3];
    *(half4v*)(d + i) = h;
  }
}

// ------------------------------------------------ shared 128x128 GEMM tile body
template <typename OUT>
__device__ __forceinline__ void gemm_tile(half_t* As, half_t* Bs,
                                          const half_t* __restrict__ A,
                                          const half_t* __restrict__ Bt,
                                          const float* __restrict__ bias,
                                          OUT* __restrict__ C, int bm, int bn) {
  const int K = DM, N = DM;
  const int tid = threadIdx.x, wid = tid >> 6, l = tid & 63;
  const int wm = (wid >> 1) * 64, wn = (wid & 1) * 64;
  const int l15 = l & 15, l4 = l >> 4;
  float4v acc[4][4] = {};

  const half_t* ga = A + (long)(bm + wid * 32 + (l >> 2)) * K + (l & 3) * 8;
  const half_t* gb = Bt + (long)(bn + wid * 32 + (l >> 2)) * K + (l & 3) * 8;
  char* lAs = (char*)As + wid * 2048;
  char* lBs = (char*)Bs + wid * 2048;
  const long rowstep = 16l * K;

  for (int k0 = 0; k0 < K; k0 += 32) {
    gload16(ga + k0, lAs);
    gload16(ga + rowstep + k0, lAs + 1024);
    gload16(gb + k0, lBs);
    gload16(gb + rowstep + k0, lBs + 1024);
    __syncthreads();
    half8v af[4], bf[4];
#pragma unroll
    for (int i = 0; i < 4; i++) af[i] = *(const half8v*)&As[(wm + i * 16 + l15) * 32 + l4 * 8];
#pragma unroll
    for (int j = 0; j < 4; j++) bf[j] = *(const half8v*)&Bs[(wn + j * 16 + l15) * 32 + l4 * 8];
#pragma unroll
    for (int i = 0; i < 4; i++)
#pragma unroll
      for (int j = 0; j < 4; j++)
        acc[i][j] = __builtin_amdgcn_mfma_f32_16x16x32_f16(af[i], bf[j], acc[i][j], 0, 0, 0);
    __syncthreads();
  }
#pragma unroll
  for (int i = 0; i < 4; i++)
#pragma unroll
    for (int j = 0; j < 4; j++) {
      int row = bm + wm + i * 16 + l4 * 4;
      int col = bn + wn + j * 16 + l15;
      float bv = bias ? bias[col] : 0.0f;
#pragma unroll
      for (int r = 0; r < 4; r++) {
        float v = acc[i][j][r] + bv;
        C[(long)(row + r) * N + col] = (OUT)v;
      }
    }
}

// fused triple-GEMM (same A, 3 weights/biases/outputs); grid.x = 72
__global__ __launch_bounds__(256) void gemm3_kernel(const half_t* __restrict__ A,
                                                    const half_t* __restrict__ W0,
                                                    const half_t* __restrict__ W1,
                                                    const half_t* __restrict__ W2,
                                                    const float* b0, const float* b1, const float* b2,
                                                    half_t* O0, half_t* O1, half_t* O2) {
  __shared__ half_t As[128 * 32];
  __shared__ half_t Bs[128 * 32];
  int sel = blockIdx.x / 24;
  const half_t* Bt = sel == 0 ? W0 : (sel == 1 ? W1 : W2);
  const float* bias = sel == 0 ? b0 : (sel == 1 ? b1 : b2);
  half_t* C = sel == 0 ? O0 : (sel == 1 ? O1 : O2);
  gemm_tile<half_t>(As, Bs, A, Bt, bias, C, blockIdx.y * 128, (blockIdx.x % 24) * 128);
}

// fused output projections; grid (24, 20): y<16 img, y>=16 enc
__global__ __launch_bounds__(256) void gemm_out_kernel(const half_t* __restrict__ ocomb,
                                                       const half_t* __restrict__ Wo_h,
                                                       const half_t* __restrict__ Wao_h,
                                                       const float* bo, const float* bao,
                                                       float* out_img, float* out_enc) {
  __shared__ half_t As[128 * 32];
  __shared__ half_t Bs[128 * 32];
  int y = blockIdx.y;
  bool enc = y >= 16;
  const half_t* A = enc ? ocomb : ocomb + (long)S_TXT * DM;
  int bm = (enc ? (y - 16) : y) * 128;
  gemm_tile<float>(As, Bs, A, enc ? Wao_h : Wo_h, enc ? bao : bo,
                   enc ? out_enc : out_img, bm, blockIdx.x * 128);
}

// ------------------------------------------------ ip projections (M=4, f32 direct)
__global__ __launch_bounds__(256) void ip_proj_kernel(const float* __restrict__ x,
                                                      const float* __restrict__ W,
                                                      float* __restrict__ out) {
  int n = blockIdx.x * 4 + (threadIdx.x >> 6);
  int l = threadIdx.x & 63;
  const float* wr = W + (long)n * DM;
  float acc[4] = {0.f, 0.f, 0.f, 0.f};
  for (int k = l * 4; k < DM; k += 256) {
    float4v wv = *(const float4v*)(wr + k);
#pragma unroll
    for (int p = 0; p < 4; p++) {
      float4v xv = *(const float4v*)(x + p * DM + k);
      acc[p] += wv[0] * xv[0] + wv[1] * xv[1] + wv[2] * xv[2] + wv[3] * xv[3];
    }
  }
#pragma unroll
  for (int off = 32; off; off >>= 1)
#pragma unroll
    for (int p = 0; p < 4; p++) acc[p] += __shfl_xor(acc[p], off, 64);
  if (l == 0)
#pragma unroll
    for (int p = 0; p < 4; p++) out[p * DM + n] = acc[p];
}

// ------------------------------------------------ ip k-norm (eps 1e-5) + v convert
__global__ void ip_norm_kernel(const float* __restrict__ kr, const float* __restrict__ vr,
                               half_t* __restrict__ kh, half_t* __restrict__ vh) {
  int t = blockIdx.x;
  int l = threadIdx.x;
  int d = l * 2;
  if (t < 96) {
    int base = (t / 24) * DM + (t % 24) * HD;
    float x0 = kr[base + d], x1 = kr[base + d + 1];
    float ss = x0 * x0 + x1 * x1;
#pragma unroll
    for (int off = 32; off; off >>= 1) ss += __shfl_xor(ss, off, 64);
    float r = rsqrtf(ss * (1.0f / HD) + 1e-5f);
    kh[base + d] = (half_t)(x0 * r);
    kh[base + d + 1] = (half_t)(x1 * r);
  } else {
    int t2 = t - 96;
    int base = (t2 / 24) * DM + (t2 % 24) * HD;
    vh[base + d] = (half_t)vr[base + d];
    vh[base + d + 1] = (half_t)vr[base + d + 1];
  }
}

// ------------------------------------------------ prep: rmsnorm + rope + concat q,k
__global__ __launch_bounds__(256) void prep_kernel(
    const half_t* __restrict__ qraw, const half_t* __restrict__ kraw,
    const half_t* __restrict__ eq, const half_t* __restrict__ ek,
    const float* __restrict__ nqw, const float* __restrict__ nkw,
    const float* __restrict__ naqw, const float* __restrict__ nakw,
    const float* __restrict__ cosb, const float* __restrict__ sinb,
    half_t* __restrict__ qcat, half_t* __restrict__ kcat, half_t* __restrict__ qnr) {
  int task = blockIdx.x * 4 + (threadIdx.x >> 6);
  int l = threadIdx.x & 63;
  int s = task / NH, h = task - (task / NH) * NH;
  int d = l * 2;
  const half_t *qs, *ks;
  const float *wq, *wk;
  if (s < S_TXT) {
    long base = (long)s * DM + h * HD;
    qs = eq + base; ks = ek + base;
    wq = naqw; wk = nakw;
  } else {
    long base = (long)(s - S_TXT) * DM + h * HD;
    qs = qraw + base; ks = kraw + base;
    wq = nqw; wk = nkw;
  }
  half2v qv = *(const half2v*)(qs + d);
  half2v kv = *(const half2v*)(ks + d);
  float q0 = (float)qv[0], q1 = (float)qv[1];
  float k0 = (float)kv[0], k1 = (float)kv[1];
  float ssq = q0 * q0 + q1 * q1;
  float ssk = k0 * k0 + k1 * k1;
#pragma unroll
  for (int off = 32; off; off >>= 1) {
    ssq += __shfl_xor(ssq, off, 64);
    ssk += __shfl_xor(ssk, off, 64);
  }
  float rq = rsqrtf(ssq * (1.0f / HD) + 1e-6f);
  float rk = rsqrtf(ssk * (1.0f / HD) + 1e-6f);
  float qn0 = q0 * rq * wq[d], qn1 = q1 * rq * wq[d + 1];
  float kn0 = k0 * rk * wk[d], kn1 = k1 * rk * wk[d + 1];
  if (s >= S_TXT) {
    half2v o; o[0] = (half_t)qn0; o[1] = (half_t)qn1;
    *(half2v*)(qnr + ((long)h * S_IMG + (s - S_TXT)) * HD + d) = o;
  }
  float c0 = cosb[s * HD + d], c1 = cosb[s * HD + d + 1];
  float s0 = sinb[s * HD + d], s1 = sinb[s * HD + d + 1];
  float qo0 = qn0 * c0 - qn1 * s0, qo1 = qn1 * c1 + qn0 * s1;
  float ko0 = kn0 * c0 - kn1 * s0, ko1 = kn1 * c1 + kn0 * s1;
  long ci = ((long)h * S_TOT + s) * HD + d;
  half2v oq; oq[0] = (half_t)qo0; oq[1] = (half_t)qo1;
  half2v ok; ok[0] = (half_t)ko0; ok[1] = (half_t)ko1;
  *(half2v*)(qcat + ci) = oq;
  *(half2v*)(kcat + ci) = ok;
}

// ------------------------------------------------ V transpose: [s][h*HD+d] -> [h][d][s]
__global__ __launch_bounds__(256) void vtrans_kernel(const half_t* __restrict__ ev,
                                                     const half_t* __restrict__ vraw,
                                                     half_t* __restrict__ vcatT) {
  __shared__ half_t T[64][136];  // 272B stride: 16B-aligned rows
  int h = blockIdx.y, sb = blockIdx.x * 64;
  int t = threadIdx.x;
#pragma unroll
  for (int i = 0; i < 4; i++) {
    int c = t + i * 256;            // 0..1023 : 64 rows x 16 chunks
    int row = c >> 4, col = (c & 15) * 8;
    int s = sb + row;
    const half_t* src = (s < S_TXT) ? ev + (long)s * DM + h * HD + col
                                    : vraw + (long)(s - S_TXT) * DM + h * HD + col;
    *(half8v*)&T[row][col] = *(const half8v*)src;
  }
  __syncthreads();
#pragma unroll
  for (int i = 0; i < 4; i++) {
    int c = t + i * 256;            // 0..1023 : 128 d-rows x 8 chunks
    int d = c >> 3, sc = (c & 7) * 8;
    half8v v;
#pragma unroll
    for (int j = 0; j < 8; j++) v[j] = T[sc + j][d];
    *(half8v*)(vcatT + ((long)h * HD + d) * S_TOT + sb + sc) = v;
  }
}

// ------------------------------------------------ ip attention (4 keys)
__global__ __launch_bounds__(256) void ip_attn_kernel(const half_t* __restrict__ qnr,
                                                      const half_t* __restrict__ kh,
                                                      const half_t* __restrict__ vh,
                                                      half_t* __restrict__ ipout) {
  int task = blockIdx.x * 4 + (threadIdx.x >> 6);
  int l = threadIdx.x & 63;
  int h = task >> 11;
  int s = task & 2047;
  int d = l * 2;
  half2v qv = *(const half2v*)(qnr + ((long)h * S_IMG + s) * HD + d);
  float q0 = (float)qv[0], q1 = (float)qv[1];
  float sc[4];
#pragma unroll
  for (int p = 0; p < 4; p++) {
    half2v kv = *(const half2v*)(kh + p * DM + h * HD + d);
    sc[p] = q0 * (float)kv[0] + q1 * (float)kv[1];
  }
#pragma unroll
  for (int off = 32; off; off >>= 1)
#pragma unroll
    for (int p = 0; p < 4; p++) sc[p] += __shfl_xor(sc[p], off, 64);
  float m = fmaxf(fmaxf(sc[0], sc[1]), fmaxf(sc[2], sc[3]));
  float e[4], sum = 0.f;
#pragma unroll
  for (int p = 0; p < 4; p++) { e[p] = __expf((sc[p] - m) * 0.088388347648318447f); sum += e[p]; }
  float inv = 1.0f / sum;
  float o0 = 0.f, o1 = 0.f;
#pragma unroll
  for (int p = 0; p < 4; p++) {
    half2v vv = *(const half2v*)(vh + p * DM + h * HD + d);
    o0 += e[p] * (float)vv[0];
    o1 += e[p] * (float)vv[1];
  }
  o0 *= inv; o1 *= inv;
  half2v ov; ov[0] = (half_t)o0; ov[1] = (half_t)o1;
  *(half2v*)(ipout + (long)s * DM + h * HD + d) = ov;
}

// ------------------------------------------------ flash attention, KVBLK=64
__global__ __launch_bounds__(256) void flash_kernel(const half_t* __restrict__ qcat,
                                                    const half_t* __restrict__ kcat,
                                                    const half_t* __restrict__ vcatT,
                                                    const half_t* __restrict__ ipout,
                                                    const float* __restrict__ lsp,
                                                    half_t* __restrict__ ocomb) {
  __shared__ half_t Ks[64 * 128];   // rows 256B, swizzled
  __shared__ half_t Vs[128 * 64];   // rows 128B, swizzled
  __shared__ half_t Pl[4][16 * 72];
  const int h = blockIdx.y, qb = blockIdx.x;
  const int tid = threadIdx.x, wid = tid >> 6, l = tid & 63;
  const int l15 = l & 15, l4 = l >> 4;
  const float CEXP = 0.12754137969983614f;  // (1/sqrt(128)) * log2(e)

  half8v qf[4];
  {
    int qrow = qb * 64 + wid * 16 + l15;
    const half_t* qp = qcat + ((long)h * S_TOT + qrow) * HD;
#pragma unroll
    for (int ks = 0; ks < 4; ks++) qf[ks] = *(const half8v*)(qp + ks * 32 + l4 * 8);
  }
  float4v o[8] = {};
  float mreg[4] = {-3.0e38f, -3.0e38f, -3.0e38f, -3.0e38f};
  float lreg[4] = {0.f, 0.f, 0.f, 0.f};
  const float ls = lsp[0];

  const char* kb = (const char*)(kcat + (long)h * S_TOT * HD);
  const char* vb = (const char*)(vcatT + (long)h * HD * S_TOT);
  char* ksl = (char*)Ks + wid * 4096;
  char* vsl = (char*)Vs + wid * 4096;
  int kof[4];
  long vof[4];
#pragma unroll
  for (int c = 0; c < 4; c++) {
    int L = wid * 4096 + c * 1024 + l * 16;
    kof[c] = L ^ (((L >> 8) & 7) << 4);
    int vrow = L >> 7;
    vof[c] = (long)vrow * (S_TOT * 2) + ((L & 127) ^ ((vrow & 7) << 4));
  }

  for (int kt = 0; kt < S_TOT; kt += 64) {
#pragma unroll
    for (int c = 0; c < 4; c++) gload16(kb + (long)kt * 256 + kof[c], ksl + c * 1024);
#pragma unroll
    for (int c = 0; c < 4; c++) gload16(vb + vof[c] + kt * 2, vsl + c * 1024);
    __syncthreads();

    // QK^T: S tile 16(q) x 64(k)
    float4v s[4] = {};
#pragma unroll
    for (int nb = 0; nb < 4; nb++) {
      int kcol = nb * 16 + l15;
      int rb = kcol << 8;
      int sw = (kcol & 7) << 4;
#pragma unroll
      for (int kk = 0; kk < 4; kk++) {
        half8v kf = *(const half8v*)((const char*)Ks + rb + ((kk * 64 + l4 * 16) ^ sw));
        s[nb] = __builtin_amdgcn_mfma_f32_16x16x32_f16(qf[kk], kf, s[nb], 0, 0, 0);
      }
    }
    // online softmax; rows q = l4*4+r, cols k = nb*16 + l15
    float mt[4];
#pragma unroll
    for (int r = 0; r < 4; r++)
      mt[r] = fmaxf(fmaxf(s[0][r], s[1][r]), fmaxf(s[2][r], s[3][r]));
#pragma unroll
    for (int off = 8; off; off >>= 1)
#pragma unroll
      for (int r = 0; r < 4; r++) mt[r] = fmaxf(mt[r], __shfl_xor(mt[r], off, 16));
    float al[4];
#pragma unroll
    for (int r = 0; r < 4; r++) {
      float mn = fmaxf(mreg[r], mt[r]);
      al[r] = exp2f((mreg[r] - mn) * CEXP);
      mreg[r] = mn;
    }
    float p[4][4], rs[4];
#pragma unroll
    for (int nb = 0; nb < 4; nb++)
#pragma unroll
      for (int r = 0; r < 4; r++) p[nb][r] = exp2f((s[nb][r] - mreg[r]) * CEXP);
#pragma unroll
    for (int r = 0; r < 4; r++) rs[r] = (p[0][r] + p[1][r]) + (p[2][r] + p[3][r]);
#pragma unroll
    for (int off = 8; off; off >>= 1)
#pragma unroll
      for (int r = 0; r < 4; r++) rs[r] += __shfl_xor(rs[r], off, 16);
#pragma unroll
    for (int r = 0; r < 4; r++) lreg[r] = lreg[r] * al[r] + rs[r];
#pragma unroll
    for (int cb = 0; cb < 8; cb++)
#pragma unroll
      for (int r = 0; r < 4; r++) o[cb][r] *= al[r];
    // P -> per-wave LDS (transpose to A-operand layout)
#pragma unroll
    for (int nb = 0; nb < 4; nb++)
#pragma unroll
      for (int r = 0; r < 4; r++)
        Pl[wid][(l4 * 4 + r) * 72 + nb * 16 + l15] = (half_t)p[nb][r];
    // PV: o[cb] over d = cb*16 + l15
#pragma unroll
    for (int kk2 = 0; kk2 < 2; kk2++) {
      half8v pa = *(const half8v*)&Pl[wid][l15 * 72 + kk2 * 32 + l4 * 8];
#pragma unroll
      for (int cb = 0; cb < 8; cb++) {
        int row = cb * 16 + l15;
        half8v vf = *(const half8v*)((const char*)Vs + (row << 7) +
                                     ((kk2 * 64 + l4 * 16) ^ ((row & 7) << 4)));
        o[cb] = __builtin_amdgcn_mfma_f32_16x16x32_f16(pa, vf, o[cb], 0, 0, 0);
      }
    }
    __syncthreads();
  }
  // epilogue
#pragma unroll
  for (int r = 0; r < 4; r++) {
    float inv = 1.0f / lreg[r];
    int s = qb * 64 + wid * 16 + l4 * 4 + r;
#pragma unroll
    for (int cb = 0; cb < 8; cb++) {
      int col = h * HD + cb * 16 + l15;
      float val = o[cb][r] * inv;
      if (s >= S_TXT) val += ls * (float)ipout[(long)(s - S_TXT) * DM + col];
      ocomb[(long)s * DM + col] = (half_t)val;
    }
  }
}

// ================================================================ host
extern "C" void kernel_launch(void* const* d_in, const int* in_sizes, int n_in,
                              void* d_out, int out_size, void* d_ws, size_t ws_size,
                              hipStream_t stream) {
  (void)in_sizes; (void)n_in; (void)out_size; (void)ws_size;
  const float* hs    = (const float*)d_in[0];
  const float* enc   = (const float*)d_in[1];
  const float* ipenc = (const float*)d_in[2];
  const float* lsc   = (const float*)d_in[3];
  const float* Wq  = (const float*)d_in[4];  const float* bq  = (const float*)d_in[5];
  const float* Wk  = (const float*)d_in[6];  const float* bk  = (const float*)d_in[7];
  const float* Wv  = (const float*)d_in[8];  const float* bv  = (const float*)d_in[9];
  const float* nqw = (const float*)d_in[10]; const float* nkw = (const float*)d_in[11];
  const float* Waq = (const float*)d_in[12]; const float* baq = (const float*)d_in[13];
  const float* Wak = (const float*)d_in[14]; const float* bak = (const float*)d_in[15];
  const float* Wav = (const float*)d_in[16]; const float* bav = (const float*)d_in[17];
  const float* naqw= (const float*)d_in[18]; const float* nakw= (const float*)d_in[19];
  const float* Wkip= (const float*)d_in[20]; const float* Wvip= (const float*)d_in[21];
  const float* Wo  = (const float*)d_in[22]; const float* bo  = (const float*)d_in[23];
  const float* Wao = (const float*)d_in[24]; const float* bao = (const float*)d_in[25];
  const float* cosb= (const float*)d_in[26]; const float* sinb= (const float*)d_in[27];

  const size_t WSZ = (size_t)DM * DM;
  const size_t HSZ = (size_t)S_IMG * DM;
  const size_t ESZ = (size_t)S_TXT * DM;
  const size_t CSZ = (size_t)NH * S_TOT * HD;

  half_t* base = (half_t*)d_ws;
  half_t* W3    = base;                 // 3*WSZ: rotating weight slots
  half_t* hs_h  = W3 + 3 * WSZ;         // HSZ; later reused as qnr
  half_t* enc_h = hs_h + HSZ;           // ESZ; later reused as ip scratch
  half_t* qkvr  = enc_h + ESZ;          // 3*HSZ: q/k/v raw; later ipout+ocomb
  half_t* eqkv  = qkvr + 3 * HSZ;       // 3*ESZ: eq/ek/ev
  half_t* qcat  = eqkv + 3 * ESZ;       // CSZ
  half_t* kcat  = qcat + CSZ;           // CSZ
  half_t* vcatT = kcat + CSZ;           // CSZ

  half_t* q_raw = qkvr;
  half_t* k_raw = qkvr + HSZ;
  half_t* v_raw = qkvr + 2 * HSZ;
  half_t* eq_r  = eqkv;
  half_t* ek_r  = eqkv + ESZ;
  half_t* ev_r  = eqkv + 2 * ESZ;
  // aliases (stream-order safe)
  half_t* qnr   = hs_h;
  half_t* ipout = qkvr;
  half_t* ocomb = qkvr + HSZ;
  float*  ipk_raw = (float*)enc_h;
  float*  ipv_raw = ipk_raw + 4 * DM;
  half_t* ipk_h  = enc_h + 16 * DM;
  half_t* ipv_h  = ipk_h + 4 * DM;

  // activations -> f16
  cvt_kernel<<<1024, 256, 0, stream>>>(hs, hs_h, (int)HSZ);
  cvt_kernel<<<512, 256, 0, stream>>>(enc, enc_h, (int)ESZ);

  // img QKV (fused)
  cvt_kernel<<<2048, 256, 0, stream>>>(Wq, W3, (int)WSZ);
  cvt_kernel<<<2048, 256, 0, stream>>>(Wk, W3 + WSZ, (int)WSZ);
  cvt_kernel<<<2048, 256, 0, stream>>>(Wv, W3 + 2 * WSZ, (int)WSZ);
  gemm3_kernel<<<dim3(72, 16), 256, 0, stream>>>(hs_h, W3, W3 + WSZ, W3 + 2 * WSZ,
                                                 bq, bk, bv, q_raw, k_raw, v_raw);
  // enc QKV (fused)
  cvt_kernel<<<2048, 256, 0, stream>>>(Waq, W3, (int)WSZ);
  cvt_kernel<<<2048, 256, 0, stream>>>(Wak, W3 + WSZ, (int)WSZ);
  cvt_kernel<<<2048, 256, 0, stream>>>(Wav, W3 + 2 * WSZ, (int)WSZ);
  gemm3_kernel<<<dim3(72, 4), 256, 0, stream>>>(enc_h, W3, W3 + WSZ, W3 + 2 * WSZ,
                                                baq, bak, bav, eq_r, ek_r, ev_r);
  // ip path
  ip_proj_kernel<<<768, 256, 0, stream>>>(ipenc, Wkip, ipk_raw);
  ip_proj_kernel<<<768, 256, 0, stream>>>(ipenc, Wvip, ipv_raw);
  ip_norm_kernel<<<192, 64, 0, stream>>>(ipk_raw, ipv_raw, ipk_h, ipv_h);

  // rmsnorm + rope + concat (q,k); V transposed separately
  prep_kernel<<<(S_TOT * NH) / 4, 256, 0, stream>>>(q_raw, k_raw, eq_r, ek_r,
                                                    nqw, nkw, naqw, nakw, cosb, sinb,
                                                    qcat, kcat, qnr);
  vtrans_kernel<<<dim3(S_TOT / 64, NH), 256, 0, stream>>>(ev_r, v_raw, vcatT);

  // ip attention (overwrites q_raw region)
  ip_attn_kernel<<<(NH * S_IMG) / 4, 256, 0, stream>>>(qnr, ipk_h, ipv_h, ipout);

  // main flash attention (+ fold ls*ip_out)
  flash_kernel<<<dim3(S_TOT / 64, NH), 256, 0, stream>>>(qcat, kcat, vcatT, ipout, lsc, ocomb);

  // output projections (fused img+enc) -> d_out f32
  float* out_img = (float*)d_out;
  float* out_enc = (float*)d_out + (size_t)S_IMG * DM;
  cvt_kernel<<<2048, 256, 0, stream>>>(Wo, W3, (int)WSZ);
  cvt_kernel<<<2048, 256, 0, stream>>>(Wao, W3 + WSZ, (int)WSZ);
  gemm_out_kernel<<<dim3(24, 20), 256, 0, stream>>>(ocomb, W3, W3 + WSZ, bo, bao,
                                                    out_img, out_enc);
}

// Round 4
// 685.910 us; speedup vs baseline: 1.5688x; 1.0515x over previous
//
#include <hip/hip_runtime.h>

typedef _Float16 half_t;
typedef _Float16 half2v __attribute__((ext_vector_type(2)));
typedef _Float16 half4v __attribute__((ext_vector_type(4)));
typedef _Float16 half8v __attribute__((ext_vector_type(8)));
typedef float    float4v __attribute__((ext_vector_type(4)));
typedef short    short8v __attribute__((ext_vector_type(8)));

#define S_IMG 2048
#define S_TXT 512
#define S_TOT 2560
#define NH    24
#define HD    128
#define DM    3072

// async global->LDS, 16B per lane, wave-uniform LDS base (+ lane*16 by HW)
__device__ __forceinline__ void gload16(const void* g, void* l) {
  __builtin_amdgcn_global_load_lds(
      (const __attribute__((address_space(1))) unsigned int*)g,
      (__attribute__((address_space(3))) unsigned int*)l, 16, 0, 0);
}

// ---------------------------------------------------------------- f32 -> f16
__global__ void cvt_kernel(const float* __restrict__ s, half_t* __restrict__ d, int n) {
  int i = (blockIdx.x * 256 + threadIdx.x) * 4;
  int stride = gridDim.x * 256 * 4;
  for (; i < n; i += stride) {
    float4v v = *(const float4v*)(s + i);
    half4v h;
    h[0] = (half_t)v[0]; h[1] = (half_t)v[1]; h[2] = (half_t)v[2]; h[3] = (half_t)v[3];
    *(half4v*)(d + i) = h;
  }
}

// ------------------------------------------------ shared 128x128 GEMM tile body
template <typename OUT>
__device__ __forceinline__ void gemm_tile(half_t* As, half_t* Bs,
                                          const half_t* __restrict__ A,
                                          const half_t* __restrict__ Bt,
                                          const float* __restrict__ bias,
                                          OUT* __restrict__ C, int bm, int bn) {
  const int K = DM, N = DM;
  const int tid = threadIdx.x, wid = tid >> 6, l = tid & 63;
  const int wm = (wid >> 1) * 64, wn = (wid & 1) * 64;
  const int l15 = l & 15, l4 = l >> 4;
  float4v acc[4][4] = {};

  const half_t* ga = A + (long)(bm + wid * 32 + (l >> 2)) * K + (l & 3) * 8;
  const half_t* gb = Bt + (long)(bn + wid * 32 + (l >> 2)) * K + (l & 3) * 8;
  char* lAs = (char*)As + wid * 2048;
  char* lBs = (char*)Bs + wid * 2048;
  const long rowstep = 16l * K;

  for (int k0 = 0; k0 < K; k0 += 32) {
    gload16(ga + k0, lAs);
    gload16(ga + rowstep + k0, lAs + 1024);
    gload16(gb + k0, lBs);
    gload16(gb + rowstep + k0, lBs + 1024);
    __syncthreads();
    half8v af[4], bf[4];
#pragma unroll
    for (int i = 0; i < 4; i++) af[i] = *(const half8v*)&As[(wm + i * 16 + l15) * 32 + l4 * 8];
#pragma unroll
    for (int j = 0; j < 4; j++) bf[j] = *(const half8v*)&Bs[(wn + j * 16 + l15) * 32 + l4 * 8];
#pragma unroll
    for (int i = 0; i < 4; i++)
#pragma unroll
      for (int j = 0; j < 4; j++)
        acc[i][j] = __builtin_amdgcn_mfma_f32_16x16x32_f16(af[i], bf[j], acc[i][j], 0, 0, 0);
    __syncthreads();
  }
#pragma unroll
  for (int i = 0; i < 4; i++)
#pragma unroll
    for (int j = 0; j < 4; j++) {
      int row = bm + wm + i * 16 + l4 * 4;
      int col = bn + wn + j * 16 + l15;
      float bv = bias ? bias[col] : 0.0f;
#pragma unroll
      for (int r = 0; r < 4; r++) {
        float v = acc[i][j][r] + bv;
        C[(long)(row + r) * N + col] = (OUT)v;
      }
    }
}

// fused triple-GEMM (same A, 3 weights/biases/outputs); grid.x = 72
__global__ __launch_bounds__(256) void gemm3_kernel(const half_t* __restrict__ A,
                                                    const half_t* __restrict__ W0,
                                                    const half_t* __restrict__ W1,
                                                    const half_t* __restrict__ W2,
                                                    const float* b0, const float* b1, const float* b2,
                                                    half_t* O0, half_t* O1, half_t* O2) {
  __shared__ half_t As[128 * 32];
  __shared__ half_t Bs[128 * 32];
  int sel = blockIdx.x / 24;
  const half_t* Bt = sel == 0 ? W0 : (sel == 1 ? W1 : W2);
  const float* bias = sel == 0 ? b0 : (sel == 1 ? b1 : b2);
  half_t* C = sel == 0 ? O0 : (sel == 1 ? O1 : O2);
  gemm_tile<half_t>(As, Bs, A, Bt, bias, C, blockIdx.y * 128, (blockIdx.x % 24) * 128);
}

// fused output projections; grid (24, 20): y<16 img, y>=16 enc
__global__ __launch_bounds__(256) void gemm_out_kernel(const half_t* __restrict__ ocomb,
                                                       const half_t* __restrict__ Wo_h,
                                                       const half_t* __restrict__ Wao_h,
                                                       const float* bo, const float* bao,
                                                       float* out_img, float* out_enc) {
  __shared__ half_t As[128 * 32];
  __shared__ half_t Bs[128 * 32];
  int y = blockIdx.y;
  bool enc = y >= 16;
  const half_t* A = enc ? ocomb : ocomb + (long)S_TXT * DM;
  int bm = (enc ? (y - 16) : y) * 128;
  gemm_tile<float>(As, Bs, A, enc ? Wao_h : Wo_h, enc ? bao : bo,
                   enc ? out_enc : out_img, bm, blockIdx.x * 128);
}

// ------------------------------------------------ ip projections (M=4, f32 direct)
__global__ __launch_bounds__(256) void ip_proj_kernel(const float* __restrict__ x,
                                                      const float* __restrict__ W,
                                                      float* __restrict__ out) {
  int n = blockIdx.x * 4 + (threadIdx.x >> 6);
  int l = threadIdx.x & 63;
  const float* wr = W + (long)n * DM;
  float acc[4] = {0.f, 0.f, 0.f, 0.f};
  for (int k = l * 4; k < DM; k += 256) {
    float4v wv = *(const float4v*)(wr + k);
#pragma unroll
    for (int p = 0; p < 4; p++) {
      float4v xv = *(const float4v*)(x + p * DM + k);
      acc[p] += wv[0] * xv[0] + wv[1] * xv[1] + wv[2] * xv[2] + wv[3] * xv[3];
    }
  }
#pragma unroll
  for (int off = 32; off; off >>= 1)
#pragma unroll
    for (int p = 0; p < 4; p++) acc[p] += __shfl_xor(acc[p], off, 64);
  if (l == 0)
#pragma unroll
    for (int p = 0; p < 4; p++) out[p * DM + n] = acc[p];
}

// ------------------------------------------------ ip k-norm (eps 1e-5) + v convert
__global__ void ip_norm_kernel(const float* __restrict__ kr, const float* __restrict__ vr,
                               half_t* __restrict__ kh, half_t* __restrict__ vh) {
  int t = blockIdx.x;
  int l = threadIdx.x;
  int d = l * 2;
  if (t < 96) {
    int base = (t / 24) * DM + (t % 24) * HD;
    float x0 = kr[base + d], x1 = kr[base + d + 1];
    float ss = x0 * x0 + x1 * x1;
#pragma unroll
    for (int off = 32; off; off >>= 1) ss += __shfl_xor(ss, off, 64);
    float r = rsqrtf(ss * (1.0f / HD) + 1e-5f);
    kh[base + d] = (half_t)(x0 * r);
    kh[base + d + 1] = (half_t)(x1 * r);
  } else {
    int t2 = t - 96;
    int base = (t2 / 24) * DM + (t2 % 24) * HD;
    vh[base + d] = (half_t)vr[base + d];
    vh[base + d + 1] = (half_t)vr[base + d + 1];
  }
}

// ------------------------------------------------ prep: rmsnorm + rope + concat q,k
__global__ __launch_bounds__(256) void prep_kernel(
    const half_t* __restrict__ qraw, const half_t* __restrict__ kraw,
    const half_t* __restrict__ eq, const half_t* __restrict__ ek,
    const float* __restrict__ nqw, const float* __restrict__ nkw,
    const float* __restrict__ naqw, const float* __restrict__ nakw,
    const float* __restrict__ cosb, const float* __restrict__ sinb,
    half_t* __restrict__ qcat, half_t* __restrict__ kcat, half_t* __restrict__ qnr) {
  int task = blockIdx.x * 4 + (threadIdx.x >> 6);
  int l = threadIdx.x & 63;
  int s = task / NH, h = task - (task / NH) * NH;
  int d = l * 2;
  const half_t *qs, *ks;
  const float *wq, *wk;
  if (s < S_TXT) {
    long base = (long)s * DM + h * HD;
    qs = eq + base; ks = ek + base;
    wq = naqw; wk = nakw;
  } else {
    long base = (long)(s - S_TXT) * DM + h * HD;
    qs = qraw + base; ks = kraw + base;
    wq = nqw; wk = nkw;
  }
  half2v qv = *(const half2v*)(qs + d);
  half2v kv = *(const half2v*)(ks + d);
  float q0 = (float)qv[0], q1 = (float)qv[1];
  float k0 = (float)kv[0], k1 = (float)kv[1];
  float ssq = q0 * q0 + q1 * q1;
  float ssk = k0 * k0 + k1 * k1;
#pragma unroll
  for (int off = 32; off; off >>= 1) {
    ssq += __shfl_xor(ssq, off, 64);
    ssk += __shfl_xor(ssk, off, 64);
  }
  float rq = rsqrtf(ssq * (1.0f / HD) + 1e-6f);
  float rk = rsqrtf(ssk * (1.0f / HD) + 1e-6f);
  float qn0 = q0 * rq * wq[d], qn1 = q1 * rq * wq[d + 1];
  float kn0 = k0 * rk * wk[d], kn1 = k1 * rk * wk[d + 1];
  if (s >= S_TXT) {
    half2v o; o[0] = (half_t)qn0; o[1] = (half_t)qn1;
    *(half2v*)(qnr + ((long)h * S_IMG + (s - S_TXT)) * HD + d) = o;
  }
  float c0 = cosb[s * HD + d], c1 = cosb[s * HD + d + 1];
  float s0 = sinb[s * HD + d], s1 = sinb[s * HD + d + 1];
  float qo0 = qn0 * c0 - qn1 * s0, qo1 = qn1 * c1 + qn0 * s1;
  float ko0 = kn0 * c0 - kn1 * s0, ko1 = kn1 * c1 + kn0 * s1;
  long ci = ((long)h * S_TOT + s) * HD + d;
  half2v oq; oq[0] = (half_t)qo0; oq[1] = (half_t)qo1;
  half2v ok; ok[0] = (half_t)ko0; ok[1] = (half_t)ko1;
  *(half2v*)(qcat + ci) = oq;
  *(half2v*)(kcat + ci) = ok;
}

// ------------------------------------------------ V transpose: [s][h*HD+d] -> [h][d][s]
__global__ __launch_bounds__(256) void vtrans_kernel(const half_t* __restrict__ ev,
                                                     const half_t* __restrict__ vraw,
                                                     half_t* __restrict__ vcatT) {
  __shared__ half_t T[64][136];  // 272B stride: 16B-aligned rows
  int h = blockIdx.y, sb = blockIdx.x * 64;
  int t = threadIdx.x;
#pragma unroll
  for (int i = 0; i < 4; i++) {
    int c = t + i * 256;            // 0..1023 : 64 rows x 16 chunks
    int row = c >> 4, col = (c & 15) * 8;
    int s = sb + row;
    const half_t* src = (s < S_TXT) ? ev + (long)s * DM + h * HD + col
                                    : vraw + (long)(s - S_TXT) * DM + h * HD + col;
    *(half8v*)&T[row][col] = *(const half8v*)src;
  }
  __syncthreads();
#pragma unroll
  for (int i = 0; i < 4; i++) {
    int c = t + i * 256;            // 0..1023 : 128 d-rows x 8 chunks
    int d = c >> 3, sc = (c & 7) * 8;
    half8v v;
#pragma unroll
    for (int j = 0; j < 8; j++) v[j] = T[sc + j][d];
    *(half8v*)(vcatT + ((long)h * HD + d) * S_TOT + sb + sc) = v;
  }
}

// ------------------------------------------------ ip attention (4 keys)
__global__ __launch_bounds__(256) void ip_attn_kernel(const half_t* __restrict__ qnr,
                                                      const half_t* __restrict__ kh,
                                                      const half_t* __restrict__ vh,
                                                      half_t* __restrict__ ipout) {
  int task = blockIdx.x * 4 + (threadIdx.x >> 6);
  int l = threadIdx.x & 63;
  int h = task >> 11;
  int s = task & 2047;
  int d = l * 2;
  half2v qv = *(const half2v*)(qnr + ((long)h * S_IMG + s) * HD + d);
  float q0 = (float)qv[0], q1 = (float)qv[1];
  float sc[4];
#pragma unroll
  for (int p = 0; p < 4; p++) {
    half2v kv = *(const half2v*)(kh + p * DM + h * HD + d);
    sc[p] = q0 * (float)kv[0] + q1 * (float)kv[1];
  }
#pragma unroll
  for (int off = 32; off; off >>= 1)
#pragma unroll
    for (int p = 0; p < 4; p++) sc[p] += __shfl_xor(sc[p], off, 64);
  float m = fmaxf(fmaxf(sc[0], sc[1]), fmaxf(sc[2], sc[3]));
  float e[4], sum = 0.f;
#pragma unroll
  for (int p = 0; p < 4; p++) { e[p] = __expf((sc[p] - m) * 0.088388347648318447f); sum += e[p]; }
  float inv = 1.0f / sum;
  float o0 = 0.f, o1 = 0.f;
#pragma unroll
  for (int p = 0; p < 4; p++) {
    half2v vv = *(const half2v*)(vh + p * DM + h * HD + d);
    o0 += e[p] * (float)vv[0];
    o1 += e[p] * (float)vv[1];
  }
  o0 *= inv; o1 *= inv;
  half2v ov; ov[0] = (half_t)o0; ov[1] = (half_t)o1;
  *(half2v*)(ipout + (long)s * DM + h * HD + d) = ov;
}

// ------------------------------------------------ flash attention, swapped-QK^T
// 4 waves x 32 q rows (2 tiles of 16), KVBLK=64.
// QK: mfma(K_frag, Q_frag) -> S^T: lane l15 = q, regs = k  => softmax mostly in-lane.
// P: 4x ds_write_b64 into per-wave [32][72] buffer, read back as PV A-frag.
__global__ __launch_bounds__(256) void flash_kernel(const half_t* __restrict__ qcat,
                                                    const half_t* __restrict__ kcat,
                                                    const half_t* __restrict__ vcatT,
                                                    const half_t* __restrict__ ipout,
                                                    const float* __restrict__ lsp,
                                                    half_t* __restrict__ ocomb) {
  __shared__ half_t Ks[64 * 128];   // rows 256B, swizzled
  __shared__ half_t Vs[128 * 64];   // rows 128B, swizzled
  __shared__ half_t Pw[4][32 * 72]; // per-wave P: rows 0..15 tile0, 16..31 tile1
  const int h = blockIdx.y, qb = blockIdx.x;
  const int tid = threadIdx.x, wid = tid >> 6, l = tid & 63;
  const int l15 = l & 15, l4 = l >> 4;
  const float CEXP = 0.12754137969983614f;  // (1/sqrt(128)) * log2(e)

  half8v qf[2][4];
#pragma unroll
  for (int t = 0; t < 2; t++) {
    int qrow = qb * 128 + wid * 32 + t * 16 + l15;
    const half_t* qp = qcat + ((long)h * S_TOT + qrow) * HD;
#pragma unroll
    for (int kk = 0; kk < 4; kk++) qf[t][kk] = *(const half8v*)(qp + kk * 32 + l4 * 8);
  }
  float4v o[2][8] = {};
  float mreg[2] = {-3.0e38f, -3.0e38f};
  float lreg[2] = {0.f, 0.f};
  const float ls = lsp[0];

  const char* kb = (const char*)(kcat + (long)h * S_TOT * HD);
  const char* vb = (const char*)(vcatT + (long)h * HD * S_TOT);
  char* ksl = (char*)Ks + wid * 4096;
  char* vsl = (char*)Vs + wid * 4096;
  int kof[4];
  long vof[4];
#pragma unroll
  for (int c = 0; c < 4; c++) {
    int L = wid * 4096 + c * 1024 + l * 16;
    kof[c] = L ^ (((L >> 8) & 7) << 4);
    int vrow = L >> 7;
    vof[c] = (long)vrow * (S_TOT * 2) + ((L & 127) ^ ((vrow & 7) << 4));
  }

  for (int kt = 0; kt < S_TOT; kt += 64) {
#pragma unroll
    for (int c = 0; c < 4; c++) gload16(kb + (long)kt * 256 + kof[c], ksl + c * 1024);
#pragma unroll
    for (int c = 0; c < 4; c++) gload16(vb + vof[c] + kt * 2, vsl + c * 1024);
    __syncthreads();

    // QK^T swapped: S^T tiles, lane l15 = q, k = nb*16 + l4*4 + r
    float4v s0[4] = {}, s1[4] = {};
#pragma unroll
    for (int nb = 0; nb < 4; nb++) {
      int krow = nb * 16 + l15;
      int rb = krow << 8;
      int sw = (krow & 7) << 4;
#pragma unroll
      for (int kk = 0; kk < 4; kk++) {
        half8v kf = *(const half8v*)((const char*)Ks + rb + ((kk * 64 + l4 * 16) ^ sw));
        s0[nb] = __builtin_amdgcn_mfma_f32_16x16x32_f16(kf, qf[0][kk], s0[nb], 0, 0, 0);
        s1[nb] = __builtin_amdgcn_mfma_f32_16x16x32_f16(kf, qf[1][kk], s1[nb], 0, 0, 0);
      }
    }
    // per-tile softmax (q = l15, lane-local over 16 k + 2 cross-group shfl)
#pragma unroll
    for (int t = 0; t < 2; t++) {
      float4v* st = t ? s1 : s0;
      float mt = fmaxf(fmaxf(fmaxf(st[0][0], st[0][1]), fmaxf(st[0][2], st[0][3])),
                       fmaxf(fmaxf(st[1][0], st[1][1]), fmaxf(st[1][2], st[1][3])));
      mt = fmaxf(mt, fmaxf(fmaxf(fmaxf(st[2][0], st[2][1]), fmaxf(st[2][2], st[2][3])),
                           fmaxf(fmaxf(st[3][0], st[3][1]), fmaxf(st[3][2], st[3][3]))));
      mt = fmaxf(mt, __shfl_xor(mt, 16, 64));
      mt = fmaxf(mt, __shfl_xor(mt, 32, 64));
      // defer-max: rescale only when max grew by > 8 exp2-units (P <= 256, f16-safe)
      if (__any((mt - mreg[t]) * CEXP > 8.0f)) {
        float mn = fmaxf(mreg[t], mt);
        float alv = exp2f((mreg[t] - mn) * CEXP);
        mreg[t] = mn;
        lreg[t] *= alv;
#pragma unroll
        for (int r = 0; r < 4; r++) {
          float ar = __shfl(alv, l4 * 4 + r, 64);
#pragma unroll
          for (int cb = 0; cb < 8; cb++) o[t][cb][r] *= ar;
        }
      }
      float sum = 0.f;
#pragma unroll
      for (int nb = 0; nb < 4; nb++) {
        half4v ph;
#pragma unroll
        for (int r = 0; r < 4; r++) {
          float e = exp2f((st[nb][r] - mreg[t]) * CEXP);
          sum += e;
          ph[r] = (half_t)e;
        }
        *(half4v*)&Pw[wid][(t * 16 + l15) * 72 + nb * 16 + l4 * 4] = ph;
      }
      sum += __shfl_xor(sum, 16, 64);
      sum += __shfl_xor(sum, 32, 64);
      lreg[t] += sum;
    }
    // PV: A = P rows (q=l15), B = V^T rows (d), shared vf for both tiles
    half8v pa0[2], pa1[2];
#pragma unroll
    for (int kk2 = 0; kk2 < 2; kk2++) {
      pa0[kk2] = *(const half8v*)&Pw[wid][l15 * 72 + kk2 * 32 + l4 * 8];
      pa1[kk2] = *(const half8v*)&Pw[wid][(16 + l15) * 72 + kk2 * 32 + l4 * 8];
    }
#pragma unroll
    for (int cb = 0; cb < 8; cb++) {
      int row = cb * 16 + l15;
#pragma unroll
      for (int kk2 = 0; kk2 < 2; kk2++) {
        half8v vf = *(const half8v*)((const char*)Vs + (row << 7) +
                                     ((kk2 * 64 + l4 * 16) ^ ((row & 7) << 4)));
        o[0][cb] = __builtin_amdgcn_mfma_f32_16x16x32_f16(pa0[kk2], vf, o[0][cb], 0, 0, 0);
        o[1][cb] = __builtin_amdgcn_mfma_f32_16x16x32_f16(pa1[kk2], vf, o[1][cb], 0, 0, 0);
      }
    }
    __syncthreads();
  }
  // epilogue: normalize, add ls*ip_out for img rows, write f16
#pragma unroll
  for (int t = 0; t < 2; t++) {
    float invq = 1.0f / lreg[t];
#pragma unroll
    for (int r = 0; r < 4; r++) {
      float inv = __shfl(invq, l4 * 4 + r, 64);
      int s = qb * 128 + wid * 32 + t * 16 + l4 * 4 + r;
#pragma unroll
      for (int cb = 0; cb < 8; cb++) {
        int col = h * HD + cb * 16 + l15;
        float val = o[t][cb][r] * inv;
        if (s >= S_TXT) val += ls * (float)ipout[(long)(s - S_TXT) * DM + col];
        ocomb[(long)s * DM + col] = (half_t)val;
      }
    }
  }
}

// ================================================================ host
extern "C" void kernel_launch(void* const* d_in, const int* in_sizes, int n_in,
                              void* d_out, int out_size, void* d_ws, size_t ws_size,
                              hipStream_t stream) {
  (void)in_sizes; (void)n_in; (void)out_size; (void)ws_size;
  const float* hs    = (const float*)d_in[0];
  const float* enc   = (const float*)d_in[1];
  const float* ipenc = (const float*)d_in[2];
  const float* lsc   = (const float*)d_in[3];
  const float* Wq  = (const float*)d_in[4];  const float* bq  = (const float*)d_in[5];
  const float* Wk  = (const float*)d_in[6];  const float* bk  = (const float*)d_in[7];
  const float* Wv  = (const float*)d_in[8];  const float* bv  = (const float*)d_in[9];
  const float* nqw = (const float*)d_in[10]; const float* nkw = (const float*)d_in[11];
  const float* Waq = (const float*)d_in[12]; const float* baq = (const float*)d_in[13];
  const float* Wak = (const float*)d_in[14]; const float* bak = (const float*)d_in[15];
  const float* Wav = (const float*)d_in[16]; const float* bav = (const float*)d_in[17];
  const float* naqw= (const float*)d_in[18]; const float* nakw= (const float*)d_in[19];
  const float* Wkip= (const float*)d_in[20]; const float* Wvip= (const float*)d_in[21];
  const float* Wo  = (const float*)d_in[22]; const float* bo  = (const float*)d_in[23];
  const float* Wao = (const float*)d_in[24]; const float* bao = (const float*)d_in[25];
  const float* cosb= (const float*)d_in[26]; const float* sinb= (const float*)d_in[27];

  const size_t WSZ = (size_t)DM * DM;
  const size_t HSZ = (size_t)S_IMG * DM;
  const size_t ESZ = (size_t)S_TXT * DM;
  const size_t CSZ = (size_t)NH * S_TOT * HD;

  half_t* base = (half_t*)d_ws;
  half_t* W3    = base;                 // 3*WSZ: rotating weight slots
  half_t* hs_h  = W3 + 3 * WSZ;         // HSZ; later reused as qnr
  half_t* enc_h = hs_h + HSZ;           // ESZ; later reused as ip scratch
  half_t* qkvr  = enc_h + ESZ;          // 3*HSZ: q/k/v raw; later ipout+ocomb
  half_t* eqkv  = qkvr + 3 * HSZ;       // 3*ESZ: eq/ek/ev
  half_t* qcat  = eqkv + 3 * ESZ;       // CSZ
  half_t* kcat  = qcat + CSZ;           // CSZ
  half_t* vcatT = kcat + CSZ;           // CSZ

  half_t* q_raw = qkvr;
  half_t* k_raw = qkvr + HSZ;
  half_t* v_raw = qkvr + 2 * HSZ;
  half_t* eq_r  = eqkv;
  half_t* ek_r  = eqkv + ESZ;
  half_t* ev_r  = eqkv + 2 * ESZ;
  // aliases (stream-order safe)
  half_t* qnr   = hs_h;
  half_t* ipout = qkvr;
  half_t* ocomb = qkvr + HSZ;
  float*  ipk_raw = (float*)enc_h;
  float*  ipv_raw = ipk_raw + 4 * DM;
  half_t* ipk_h  = enc_h + 16 * DM;
  half_t* ipv_h  = ipk_h + 4 * DM;

  // activations -> f16
  cvt_kernel<<<1024, 256, 0, stream>>>(hs, hs_h, (int)HSZ);
  cvt_kernel<<<512, 256, 0, stream>>>(enc, enc_h, (int)ESZ);

  // img QKV (fused)
  cvt_kernel<<<2048, 256, 0, stream>>>(Wq, W3, (int)WSZ);
  cvt_kernel<<<2048, 256, 0, stream>>>(Wk, W3 + WSZ, (int)WSZ);
  cvt_kernel<<<2048, 256, 0, stream>>>(Wv, W3 + 2 * WSZ, (int)WSZ);
  gemm3_kernel<<<dim3(72, 16), 256, 0, stream>>>(hs_h, W3, W3 + WSZ, W3 + 2 * WSZ,
                                                 bq, bk, bv, q_raw, k_raw, v_raw);
  // enc QKV (fused)
  cvt_kernel<<<2048, 256, 0, stream>>>(Waq, W3, (int)WSZ);
  cvt_kernel<<<2048, 256, 0, stream>>>(Wak, W3 + WSZ, (int)WSZ);
  cvt_kernel<<<2048, 256, 0, stream>>>(Wav, W3 + 2 * WSZ, (int)WSZ);
  gemm3_kernel<<<dim3(72, 4), 256, 0, stream>>>(enc_h, W3, W3 + WSZ, W3 + 2 * WSZ,
                                                baq, bak, bav, eq_r, ek_r, ev_r);
  // ip path
  ip_proj_kernel<<<768, 256, 0, stream>>>(ipenc, Wkip, ipk_raw);
  ip_proj_kernel<<<768, 256, 0, stream>>>(ipenc, Wvip, ipv_raw);
  ip_norm_kernel<<<192, 64, 0, stream>>>(ipk_raw, ipv_raw, ipk_h, ipv_h);

  // rmsnorm + rope + concat (q,k); V transposed separately
  prep_kernel<<<(S_TOT * NH) / 4, 256, 0, stream>>>(q_raw, k_raw, eq_r, ek_r,
                                                    nqw, nkw, naqw, nakw, cosb, sinb,
                                                    qcat, kcat, qnr);
  vtrans_kernel<<<dim3(S_TOT / 64, NH), 256, 0, stream>>>(ev_r, v_raw, vcatT);

  // ip attention (overwrites q_raw region)
  ip_attn_kernel<<<(NH * S_IMG) / 4, 256, 0, stream>>>(qnr, ipk_h, ipv_h, ipout);

  // main flash attention (+ fold ls*ip_out)
  flash_kernel<<<dim3(S_TOT / 128, NH), 256, 0, stream>>>(qcat, kcat, vcatT, ipout, lsc, ocomb);

  // output projections (fused img+enc) -> d_out f32
  float* out_img = (float*)d_out;
  float* out_enc = (float*)d_out + (size_t)S_IMG * DM;
  cvt_kernel<<<2048, 256, 0, stream>>>(Wo, W3, (int)WSZ);
  cvt_kernel<<<2048, 256, 0, stream>>>(Wao, W3 + WSZ, (int)WSZ);
  gemm_out_kernel<<<dim3(24, 20), 256, 0, stream>>>(ocomb, W3, W3 + WSZ, bo, bao,
                                                    out_img, out_enc);
}